// Round 17
// baseline (910.666 us; speedup 1.0000x reference)
//
#include <hip/hip_runtime.h>

#define NTHR  256
#define F     59
#define K0    29
#define NB    15
#define B     131072
#define RPB   64                 // rows per block (= wavefront size)
#define NBLK  (B / RPB)          // 2048 blocks
#define NSLC  8                  // f64 atomic slices; 16B slot per (feature,slice)
#define FPW   16                 // features per wave (16/16/16/11 real)
#define YSTR  66                 // ytile stride
#define KC0   32                 // Wt k-slots layer 0
#define KCN   60                 // Wt k-slots layers 1..14

// d_ws: acc[NB][F][NSLC][2] dbl | Wt | bp[15][64] f32 | hB[F][B] f32
#define ACC_PER_LAYER (F * NSLC * 2)
#define ACC_TOTAL     (NB * ACC_PER_LAYER)           // 14160 dbl = 113280 B
#define WT_OFF_B      ((size_t)ACC_TOTAL * 8)
#define WT0_FLOATS    (KC0 * 64)
#define WTN_FLOATS    (KCN * 64)
#define WT_FLOATS     (WT0_FLOATS + 14 * WTN_FLOATS)
#define BP_OFF_B      (WT_OFF_B + (size_t)WT_FLOATS * 4)
#define HB_OFF_B      (BP_OFF_B + (size_t)NB * 64 * 4)

// ---------------------------------------------------------------------------
// Wt[k][j] = W[j][k] (zero-padded to j<64, k<KC) and padded bias for ALL layers.
// ---------------------------------------------------------------------------
__global__ void transpose_w(const float* __restrict__ W0, const float* __restrict__ b0,
                            const float* __restrict__ Ws, const float* __restrict__ bs,
                            float* __restrict__ Wt, float* __restrict__ bp)
{
  const int b = blockIdx.x;
  if (b == 0) {
    for (int i = threadIdx.x; i < KC0 * 64; i += blockDim.x) {
      int k = i >> 6, j = i & 63;
      Wt[i] = (k < K0 && j < F) ? W0[j * K0 + k] : 0.f;
    }
    if (threadIdx.x < 64)
      bp[threadIdx.x] = (threadIdx.x < F) ? b0[threadIdx.x] : 0.f;
  } else {
    float* dst = Wt + WT0_FLOATS + (size_t)(b - 1) * WTN_FLOATS;
    const float* W = Ws + (size_t)(b - 1) * F * F;
    for (int i = threadIdx.x; i < KCN * 64; i += blockDim.x) {
      int k = i >> 6, j = i & 63;
      dst[i] = (k < F && j < F) ? W[j * F + k] : 0.f;
    }
    if (threadIdx.x < 64) {
      int j = threadIdx.x;
      bp[b * 64 + j] = (j < F) ? bs[(size_t)(b - 1) * F + j] : 0.f;
    }
  }
}

// ---------------------------------------------------------------------------
// In-kernel parallel stats finalize (NSLC=8): 236 threads, 2 slots each,
// combine across c = lane&3 via 2 shfl_xor (adjacent lanes), fp64 finalize.
// ---------------------------------------------------------------------------
__device__ __forceinline__ void scsh_parallel(const double* __restrict__ acc_prev,
                                              const float* __restrict__ g,
                                              const float* __restrict__ bt,
                                              float2* scsh, int tid)
{
  if (tid < 4 * F) {
    const int j = tid >> 2, c = tid & 3;
    const double* p = acc_prev + (size_t)j * (NSLC * 2) + c * 4; // 2 slots
    double s1 = p[0] + p[2];
    double s2 = p[1] + p[3];
    s1 += __shfl_xor(s1, 1, 64);  s2 += __shfl_xor(s2, 1, 64);
    s1 += __shfl_xor(s1, 2, 64);  s2 += __shfl_xor(s2, 2, 64);
    if (c == 0) {
      const double inv = 1.0 / (double)B;
      double mu   = s1 * inv;
      double var  = fma(s2, inv, -mu * mu);        // biased variance, fp64
      double rstd = 1.0 / sqrt(var + 1e-5);
      double sc   = rstd * (double)g[j];
      scsh[j] = make_float2((float)sc, (float)fma(-mu, sc, (double)bt[j]));
    }
  }
}

// ---------------------------------------------------------------------------
// One Linear+ReLU layer. Block = 64 rows; wave q owns features 16q..16q+15.
// Non-first: prologue computes scsh (parallel, ~1us) -> barrier -> free-run:
//   k-loop: raw h[k][rowbase+lane] from global (coalesced; L2-shared across
//   waves) normalized inline via scsh LDS broadcast + s_load'd Wt + 16 FMA/k.
// Epilogue: ReLU -> coalesced stores -> wave-private ytile -> 4x b128 +
// 2 shfl -> sliced f64 atomics.
// ---------------------------------------------------------------------------
template<bool FIRST>
__global__ void __launch_bounds__(NTHR, 8)
layer_kernel(const float* __restrict__ in, const float* __restrict__ Wp,
             const float* __restrict__ bp,
             const double* __restrict__ acc_prev,   // unless FIRST
             const float* __restrict__ g_prev, const float* __restrict__ bt_prev,
             float* __restrict__ hout, double* acc)
{
  __shared__ __attribute__((aligned(16))) float lds[4 * FPW * YSTR]; // 16896 B
  __shared__ __attribute__((aligned(16))) float2 scsh[64];           //   512 B

  const int tid   = threadIdx.x;
  const int lane  = tid & 63;
  const int qu    = __builtin_amdgcn_readfirstlane(tid >> 6);
  const int rowbase = blockIdx.x * RPB;
  const int slice   = blockIdx.x & (NSLC - 1);

  if (FIRST) {                                       // x row-major: LDS stage
    for (int i = tid; i < RPB * 33; i += NTHR) {
      int r = i / 33, k = i - r * 33;
      lds[i] = (k < K0) ? in[(size_t)(rowbase + r) * K0 + k] : 0.f;
    }
    __syncthreads();
  } else {
    scsh_parallel(acc_prev, g_prev, bt_prev, scsh, tid);
    __syncthreads();
  }

  const int fbase = qu * FPW;
  const float* bq = bp + fbase;                      // uniform -> s_load
  float a0=bq[0],a1=bq[1],a2=bq[2],a3=bq[3],a4=bq[4],a5=bq[5],a6=bq[6],a7=bq[7],
        a8=bq[8],a9=bq[9],a10=bq[10],a11=bq[11],a12=bq[12],a13=bq[13],a14=bq[14],a15=bq[15];

  #define FMA16(hk, wk)                                                     \
    a0  = fmaf(hk, (wk)[0],  a0);  a1  = fmaf(hk, (wk)[1],  a1);            \
    a2  = fmaf(hk, (wk)[2],  a2);  a3  = fmaf(hk, (wk)[3],  a3);            \
    a4  = fmaf(hk, (wk)[4],  a4);  a5  = fmaf(hk, (wk)[5],  a5);            \
    a6  = fmaf(hk, (wk)[6],  a6);  a7  = fmaf(hk, (wk)[7],  a7);            \
    a8  = fmaf(hk, (wk)[8],  a8);  a9  = fmaf(hk, (wk)[9],  a9);            \
    a10 = fmaf(hk, (wk)[10], a10); a11 = fmaf(hk, (wk)[11], a11);           \
    a12 = fmaf(hk, (wk)[12], a12); a13 = fmaf(hk, (wk)[13], a13);           \
    a14 = fmaf(hk, (wk)[14], a14); a15 = fmaf(hk, (wk)[15], a15);

  if (FIRST) {
    const float* hrow = lds + lane * 33;
    #pragma unroll 2
    for (int c = 0; c < 7; ++c) {                    // 28 k's
      float h0 = hrow[4*c], h1 = hrow[4*c+1], h2 = hrow[4*c+2], h3 = hrow[4*c+3];
      const float* wk = Wp + (size_t)(4 * c) * 64 + fbase;
      FMA16(h0, wk) FMA16(h1, wk + 64) FMA16(h2, wk + 128) FMA16(h3, wk + 192)
    }
    { float h28 = hrow[28];                          // tail k=28
      FMA16(h28, Wp + (size_t)28 * 64 + fbase) }
    __syncthreads();                                 // lds -> ytile reuse
  } else {
    const float* hcol = in + rowbase + lane;         // coalesced per wave
    #pragma unroll 2
    for (int c = 0; c < 14; ++c) {                   // 56 k's
      float4 sA = *(const float4*)&scsh[4*c];        // scsh[4c],scsh[4c+1]
      float4 sB = *(const float4*)&scsh[4*c+2];      // scsh[4c+2],scsh[4c+3]
      float h0 = fmaf(hcol[(size_t)(4*c)   * B], sA.x, sA.y);
      float h1 = fmaf(hcol[(size_t)(4*c+1) * B], sA.z, sA.w);
      float h2 = fmaf(hcol[(size_t)(4*c+2) * B], sB.x, sB.y);
      float h3 = fmaf(hcol[(size_t)(4*c+3) * B], sB.z, sB.w);
      const float* wk = Wp + (size_t)(4 * c) * 64 + fbase;
      FMA16(h0, wk) FMA16(h1, wk + 64) FMA16(h2, wk + 128) FMA16(h3, wk + 192)
    }
    { float4 sA = *(const float4*)&scsh[56];         // 56,57
      float2 sC = scsh[58];
      float h56 = fmaf(hcol[(size_t)56 * B], sA.x, sA.y);
      float h57 = fmaf(hcol[(size_t)57 * B], sA.z, sA.w);
      float h58 = fmaf(hcol[(size_t)58 * B], sC.x, sC.y);
      const float* wk = Wp + (size_t)56 * 64 + fbase;
      FMA16(h56, wk) FMA16(h57, wk + 64) FMA16(h58, wk + 128) }
  }
  #undef FMA16

  // ---- ReLU + coalesced stores ----
  a0=fmaxf(a0,0.f); a1=fmaxf(a1,0.f); a2=fmaxf(a2,0.f); a3=fmaxf(a3,0.f);
  a4=fmaxf(a4,0.f); a5=fmaxf(a5,0.f); a6=fmaxf(a6,0.f); a7=fmaxf(a7,0.f);
  a8=fmaxf(a8,0.f); a9=fmaxf(a9,0.f); a10=fmaxf(a10,0.f); a11=fmaxf(a11,0.f);
  a12=fmaxf(a12,0.f); a13=fmaxf(a13,0.f); a14=fmaxf(a14,0.f); a15=fmaxf(a15,0.f);

  float* op = hout + rowbase + lane;
  #define ST(j, aj) if (fbase + j < F) op[(size_t)(fbase + j) * B] = aj;
  ST(0,a0)  ST(1,a1)  ST(2,a2)  ST(3,a3)  ST(4,a4)  ST(5,a5)  ST(6,a6)  ST(7,a7)
  ST(8,a8)  ST(9,a9)  ST(10,a10) ST(11,a11) ST(12,a12) ST(13,a13) ST(14,a14) ST(15,a15)
  #undef ST

  // ---- wave-private ytile stats (no barrier: intra-wave DS ordering) ----
  float* ytq = lds + qu * (FPW * YSTR);
  ytq[0*YSTR+lane]=a0;   ytq[1*YSTR+lane]=a1;   ytq[2*YSTR+lane]=a2;
  ytq[3*YSTR+lane]=a3;   ytq[4*YSTR+lane]=a4;   ytq[5*YSTR+lane]=a5;
  ytq[6*YSTR+lane]=a6;   ytq[7*YSTR+lane]=a7;   ytq[8*YSTR+lane]=a8;
  ytq[9*YSTR+lane]=a9;   ytq[10*YSTR+lane]=a10; ytq[11*YSTR+lane]=a11;
  ytq[12*YSTR+lane]=a12; ytq[13*YSTR+lane]=a13; ytq[14*YSTR+lane]=a14;
  ytq[15*YSTR+lane]=a15;

  const int fl = lane >> 2, c = lane & 3;
  const float* yp = ytq + fl * YSTR + c * 16;
  float4 v0 = *(const float4*)(yp);
  float4 v1 = *(const float4*)(yp + 4);
  float4 v2 = *(const float4*)(yp + 8);
  float4 v3 = *(const float4*)(yp + 12);
  float s1 = ((v0.x+v0.y)+(v0.z+v0.w)) + ((v1.x+v1.y)+(v1.z+v1.w))
           + ((v2.x+v2.y)+(v2.z+v2.w)) + ((v3.x+v3.y)+(v3.z+v3.w));
  float s2 = 0.f;
  s2=fmaf(v0.x,v0.x,s2); s2=fmaf(v0.y,v0.y,s2); s2=fmaf(v0.z,v0.z,s2); s2=fmaf(v0.w,v0.w,s2);
  s2=fmaf(v1.x,v1.x,s2); s2=fmaf(v1.y,v1.y,s2); s2=fmaf(v1.z,v1.z,s2); s2=fmaf(v1.w,v1.w,s2);
  s2=fmaf(v2.x,v2.x,s2); s2=fmaf(v2.y,v2.y,s2); s2=fmaf(v2.z,v2.z,s2); s2=fmaf(v2.w,v2.w,s2);
  s2=fmaf(v3.x,v3.x,s2); s2=fmaf(v3.y,v3.y,s2); s2=fmaf(v3.z,v3.z,s2); s2=fmaf(v3.w,v3.w,s2);

  s1 += __shfl_xor(s1, 1, 64);  s2 += __shfl_xor(s2, 1, 64);
  s1 += __shfl_xor(s1, 2, 64);  s2 += __shfl_xor(s2, 2, 64);

  if (c == 0 && fbase + fl < F) {
    double* slot = acc + ((size_t)(fbase + fl) * NSLC + slice) * 2;
    atomicAdd(slot,     (double)s1);                 // hw f64 atomic
    atomicAdd(slot + 1, (double)s2);
  }
}

// ---------------------------------------------------------------------------
// Final BN: hT -> row-major out. Parallel scsh prologue, then staged write.
// ---------------------------------------------------------------------------
__global__ void __launch_bounds__(NTHR, 8)
final_tr_kernel(const float* __restrict__ hT, const double* __restrict__ acc_last,
                const float* __restrict__ g, const float* __restrict__ bt,
                float* __restrict__ out)
{
  __shared__ float2 scsh[64];
  __shared__ float  ybuf[F * 64];
  const int tid = threadIdx.x;
  const int rowbase = blockIdx.x * RPB;

  scsh_parallel(acc_last, g, bt, scsh, tid);
  // stage raw hT while scsh lands (independent)
  for (int i = tid; i < F * 16; i += NTHR) {
    int j = i >> 4, r4 = i & 15;
    float4 v = *(const float4*)(hT + (size_t)j * B + rowbase + r4 * 4);
    *(float4*)&ybuf[j * 64 + r4 * 4] = v;
  }
  __syncthreads();

  float* oblk = out + (size_t)rowbase * F;
  for (int i = tid; i < RPB * F; i += NTHR) {
    int r = i / F, j = i - r * F;
    float2 s = scsh[j];
    oblk[i] = fmaf(ybuf[j * 64 + r], s.x, s.y);
  }
}

// ---------------------------------------------------------------------------
extern "C" void kernel_launch(void* const* d_in, const int* in_sizes, int n_in,
                              void* d_out, int out_size, void* d_ws, size_t ws_size,
                              hipStream_t stream)
{
  const float* x   = (const float*)d_in[0];
  const float* W0  = (const float*)d_in[1];
  const float* b0  = (const float*)d_in[2];
  const float* g0  = (const float*)d_in[3];
  const float* bt0 = (const float*)d_in[4];
  const float* Ws  = (const float*)d_in[5];
  const float* bs  = (const float*)d_in[6];
  const float* gs  = (const float*)d_in[7];
  const float* bts = (const float*)d_in[8];
  float* out = (float*)d_out;

  double* acc = (double*)d_ws;
  float*  Wt  = (float*)((char*)d_ws + WT_OFF_B);
  float*  bp  = (float*)((char*)d_ws + BP_OFF_B);    // [NB][64]
  float*  hB  = (float*)((char*)d_ws + HB_OFF_B);    // [F][B]
  float*  hA  = out;                                 // [F][B] alias of d_out

  hipMemsetAsync(d_ws, 0, (size_t)ACC_TOTAL * sizeof(double), stream);

  transpose_w<<<NB, NTHR, 0, stream>>>(W0, b0, Ws, bs, Wt, bp);

  // layer 0: x -> hB
  layer_kernel<true><<<NBLK, NTHR, 0, stream>>>(
      x, Wt, bp, nullptr, nullptr, nullptr, hB, acc);

  // layers 1..14: barrier-light, in-kernel parallel stats finalize
  for (int b = 1; b < NB; ++b) {
    const float* gp  = (b == 1) ? g0  : gs  + (size_t)(b - 2) * F;
    const float* btp = (b == 1) ? bt0 : bts + (size_t)(b - 2) * F;
    const float* Wpb = Wt + WT0_FLOATS + (size_t)(b - 1) * WTN_FLOATS;
    const float* src = (b & 1) ? hB : hA;
    float*       dst = (b & 1) ? hA : hB;
    layer_kernel<false><<<NBLK, NTHR, 0, stream>>>(
        src, Wpb, bp + (size_t)b * 64,
        acc + (size_t)(b - 1) * ACC_PER_LAYER, gp, btp,
        dst, acc + (size_t)b * ACC_PER_LAYER);
  }

  // layer 14 wrote hB -> final BN into row-major d_out
  final_tr_kernel<<<NBLK, NTHR, 0, stream>>>(
      hB, acc + (size_t)(NB - 1) * ACC_PER_LAYER,
      gs + (size_t)(NB - 2) * F, bts + (size_t)(NB - 2) * F, out);
}

// Round 18
// 498.500 us; speedup vs baseline: 1.8268x; 1.8268x over previous
//
#include <hip/hip_runtime.h>

#define NTHR  256
#define F     59
#define K0    29
#define NB    15
#define B     131072
#define RPB   64                 // rows per block (= wavefront size)
#define NBLK  (B / RPB)          // 2048 blocks
#define NSLC  64                 // f64 atomic slices; dense 16B slot per (feature,slice)
#define FPW   16                 // features per wave (16/16/16/11 real)
#define YSTR  66                 // ytile stride
#define KC0   32                 // Wt k-slots layer 0
#define KCN   60                 // Wt k-slots layers 1..14

// d_ws: acc[NB][F][NSLC][2] dbl | Wt | bp[15][64] f32 | hB[F][B] f32
#define ACC_PER_LAYER (F * NSLC * 2)
#define ACC_TOTAL     (NB * ACC_PER_LAYER)           // 113280 dbl = 906240 B
#define WT_OFF_B      ((size_t)ACC_TOTAL * 8)
#define WT0_FLOATS    (KC0 * 64)
#define WTN_FLOATS    (KCN * 64)
#define WT_FLOATS     (WT0_FLOATS + 14 * WTN_FLOATS)
#define BP_OFF_B      (WT_OFF_B + (size_t)WT_FLOATS * 4)
#define HB_OFF_B      (BP_OFF_B + (size_t)NB * 64 * 4)

// ---------------------------------------------------------------------------
// Wt[k][j] = W[j][k] (zero-padded to j<64, k<KC). Layer 0 also pads b0.
// ---------------------------------------------------------------------------
__global__ void transpose_w(const float* __restrict__ W0, const float* __restrict__ b0,
                            const float* __restrict__ Ws,
                            float* __restrict__ Wt, float* __restrict__ bp0)
{
  const int b = blockIdx.x;
  if (b == 0) {
    for (int i = threadIdx.x; i < KC0 * 64; i += blockDim.x) {
      int k = i >> 6, j = i & 63;
      Wt[i] = (k < K0 && j < F) ? W0[j * K0 + k] : 0.f;
    }
    if (threadIdx.x < 64)
      bp0[threadIdx.x] = (threadIdx.x < F) ? b0[threadIdx.x] : 0.f;
  } else {
    float* dst = Wt + WT0_FLOATS + (size_t)(b - 1) * WTN_FLOATS;
    const float* W = Ws + (size_t)(b - 1) * F * F;
    for (int i = threadIdx.x; i < KCN * 64; i += blockDim.x) {
      int k = i >> 6, j = i & 63;
      dst[i] = (k < F && j < F) ? W[j * F + k] : 0.f;
    }
  }
}

// ---------------------------------------------------------------------------
// Fold BN(prev) into this layer's weights (in place) + fp64 bias.
// 256 threads: j = tid&63, c = tid>>6 (4-way k/slot split, LDS combine).
// ---------------------------------------------------------------------------
__global__ void fuse_w(const double* __restrict__ acc_prev,
                       const float* __restrict__ g, const float* __restrict__ bt,
                       const float* __restrict__ bias,
                       float* Wp, float* __restrict__ bp)
{
  __shared__ double part_s[4 * 64];
  __shared__ double part_ss[4 * 64];
  __shared__ double bpart[4 * 64];
  __shared__ float  scf[64];
  __shared__ double shd[64];

  const int tid = threadIdx.x;
  const int j   = tid & 63;
  const int c   = tid >> 6;

  // phase 1: 4-way parallel slot reduction (16 slots each)
  {
    const double* p = acc_prev + (size_t)j * (NSLC * 2) + c * (NSLC / 2);
    double s1 = 0.0, s2 = 0.0;
    #pragma unroll
    for (int i = 0; i < NSLC / 4; ++i) { s1 += p[2 * i]; s2 += p[2 * i + 1]; }
    part_s[c * 64 + j] = s1;
    part_ss[c * 64 + j] = s2;
  }
  __syncthreads();

  if (c == 0) {
    if (j < F) {
      double s1 = part_s[j] + part_s[64 + j] + part_s[128 + j] + part_s[192 + j];
      double s2 = part_ss[j] + part_ss[64 + j] + part_ss[128 + j] + part_ss[192 + j];
      const double inv = 1.0 / (double)B;
      double mu   = s1 * inv;
      double var  = fma(s2, inv, -mu * mu);          // biased variance, fp64
      double rstd = 1.0 / sqrt(var + 1e-5);
      double sc   = rstd * (double)g[j];
      scf[j] = (float)sc;
      shd[j] = fma(-mu, sc, (double)bt[j]);
    } else { scf[j] = 0.f; shd[j] = 0.0; }
  }
  __syncthreads();

  // phase 2: rescale W columns (4-way k split, coalesced per wave) + bias part
  double bacc = 0.0;
  for (int k = c; k < F; k += 4) {
    float w = Wp[k * 64 + j];
    bacc = fma((double)w, shd[k], bacc);
    Wp[k * 64 + j] = w * scf[k];
  }
  bpart[c * 64 + j] = bacc;
  __syncthreads();

  if (c == 0) {
    double bb = ((j < F) ? (double)bias[j] : 0.0) +
                bpart[j] + bpart[64 + j] + bpart[128 + j] + bpart[192 + j];
    bp[j] = (float)bb;
  }
}

// ---------------------------------------------------------------------------
// scsh for the FINAL BN (wave 0 of final_tr blocks): lane j loops 64 slots.
// ---------------------------------------------------------------------------
__device__ __forceinline__ void scsh_wave0(const double* __restrict__ acc_prev,
                                           const float* __restrict__ g,
                                           const float* __restrict__ bt,
                                           float2* scsh, int lane)
{
  if (lane < F) {
    const double* p = acc_prev + (size_t)lane * (NSLC * 2);
    double s1 = 0.0, s2 = 0.0;
    #pragma unroll 8
    for (int s = 0; s < NSLC; ++s) { s1 += p[2 * s]; s2 += p[2 * s + 1]; }
    const double inv = 1.0 / (double)B;
    double mu   = s1 * inv;
    double var  = fma(s2, inv, -mu * mu);
    double rstd = 1.0 / sqrt(var + 1e-5);
    double sc   = rstd * (double)g[lane];
    scsh[lane] = make_float2((float)sc, (float)fma(-mu, sc, (double)bt[lane]));
  }
}

// ---------------------------------------------------------------------------
// One Linear+ReLU layer, BARRIER-FREE (non-first). Block = 64 rows; wave q
// owns features 16q..16q+15. Waves free-run:
//   k-loop: h[k][rowbase+lane] straight from global (coalesced; L2-shared)
//   + s_load'd W' rows + 16 FMA per k.
//   Epilogue: ReLU -> coalesced stores -> wave-private ytile -> 4x b128 +
//   2 shfl -> sliced f64 atomics. FIRST layer stages x via LDS (2 barriers).
// ---------------------------------------------------------------------------
template<bool FIRST>
__global__ void __launch_bounds__(NTHR, 8)
layer_kernel(const float* __restrict__ in, const float* __restrict__ Wp,
             const float* __restrict__ bp,
             float* __restrict__ hout, double* acc)
{
  __shared__ __attribute__((aligned(16))) float lds[4 * FPW * YSTR]; // 16896 B

  const int tid   = threadIdx.x;
  const int lane  = tid & 63;
  const int qu    = __builtin_amdgcn_readfirstlane(tid >> 6);
  const int rowbase = blockIdx.x * RPB;
  const int slice   = blockIdx.x & (NSLC - 1);

  if (FIRST) {                                       // x row-major: LDS stage
    for (int i = tid; i < RPB * 33; i += NTHR) {
      int r = i / 33, k = i - r * 33;
      lds[i] = (k < K0) ? in[(size_t)(rowbase + r) * K0 + k] : 0.f;
    }
    __syncthreads();
  }

  const int fbase = qu * FPW;
  const float* bq = bp + fbase;                      // uniform -> s_load
  float a0=bq[0],a1=bq[1],a2=bq[2],a3=bq[3],a4=bq[4],a5=bq[5],a6=bq[6],a7=bq[7],
        a8=bq[8],a9=bq[9],a10=bq[10],a11=bq[11],a12=bq[12],a13=bq[13],a14=bq[14],a15=bq[15];

  #define FMA16(hk, wk)                                                     \
    a0  = fmaf(hk, (wk)[0],  a0);  a1  = fmaf(hk, (wk)[1],  a1);            \
    a2  = fmaf(hk, (wk)[2],  a2);  a3  = fmaf(hk, (wk)[3],  a3);            \
    a4  = fmaf(hk, (wk)[4],  a4);  a5  = fmaf(hk, (wk)[5],  a5);            \
    a6  = fmaf(hk, (wk)[6],  a6);  a7  = fmaf(hk, (wk)[7],  a7);            \
    a8  = fmaf(hk, (wk)[8],  a8);  a9  = fmaf(hk, (wk)[9],  a9);            \
    a10 = fmaf(hk, (wk)[10], a10); a11 = fmaf(hk, (wk)[11], a11);           \
    a12 = fmaf(hk, (wk)[12], a12); a13 = fmaf(hk, (wk)[13], a13);           \
    a14 = fmaf(hk, (wk)[14], a14); a15 = fmaf(hk, (wk)[15], a15);

  if (FIRST) {
    const float* hrow = lds + lane * 33;
    #pragma unroll 2
    for (int c = 0; c < 7; ++c) {                    // 28 k's
      float h0 = hrow[4*c], h1 = hrow[4*c+1], h2 = hrow[4*c+2], h3 = hrow[4*c+3];
      const float* wk = Wp + (size_t)(4 * c) * 64 + fbase;
      FMA16(h0, wk) FMA16(h1, wk + 64) FMA16(h2, wk + 128) FMA16(h3, wk + 192)
    }
    { float h28 = hrow[28];                          // tail k=28
      FMA16(h28, Wp + (size_t)28 * 64 + fbase) }
    __syncthreads();                                 // lds -> ytile reuse
  } else {
    const float* hcol = in + rowbase + lane;         // coalesced per wave
    #pragma unroll 2
    for (int c = 0; c < 14; ++c) {                   // 56 k's
      float h0 = hcol[(size_t)(4*c)   * B];
      float h1 = hcol[(size_t)(4*c+1) * B];
      float h2 = hcol[(size_t)(4*c+2) * B];
      float h3 = hcol[(size_t)(4*c+3) * B];
      const float* wk = Wp + (size_t)(4 * c) * 64 + fbase;
      FMA16(h0, wk) FMA16(h1, wk + 64) FMA16(h2, wk + 128) FMA16(h3, wk + 192)
    }
    { float h56 = hcol[(size_t)56 * B];              // tail 56..58
      float h57 = hcol[(size_t)57 * B];
      float h58 = hcol[(size_t)58 * B];
      const float* wk = Wp + (size_t)56 * 64 + fbase;
      FMA16(h56, wk) FMA16(h57, wk + 64) FMA16(h58, wk + 128) }
  }
  #undef FMA16

  // ---- ReLU + coalesced stores ----
  a0=fmaxf(a0,0.f); a1=fmaxf(a1,0.f); a2=fmaxf(a2,0.f); a3=fmaxf(a3,0.f);
  a4=fmaxf(a4,0.f); a5=fmaxf(a5,0.f); a6=fmaxf(a6,0.f); a7=fmaxf(a7,0.f);
  a8=fmaxf(a8,0.f); a9=fmaxf(a9,0.f); a10=fmaxf(a10,0.f); a11=fmaxf(a11,0.f);
  a12=fmaxf(a12,0.f); a13=fmaxf(a13,0.f); a14=fmaxf(a14,0.f); a15=fmaxf(a15,0.f);

  float* op = hout + rowbase + lane;
  #define ST(j, aj) if (fbase + j < F) op[(size_t)(fbase + j) * B] = aj;
  ST(0,a0)  ST(1,a1)  ST(2,a2)  ST(3,a3)  ST(4,a4)  ST(5,a5)  ST(6,a6)  ST(7,a7)
  ST(8,a8)  ST(9,a9)  ST(10,a10) ST(11,a11) ST(12,a12) ST(13,a13) ST(14,a14) ST(15,a15)
  #undef ST

  // ---- wave-private ytile stats (no barrier: intra-wave DS ordering) ----
  float* ytq = lds + qu * (FPW * YSTR);
  ytq[0*YSTR+lane]=a0;   ytq[1*YSTR+lane]=a1;   ytq[2*YSTR+lane]=a2;
  ytq[3*YSTR+lane]=a3;   ytq[4*YSTR+lane]=a4;   ytq[5*YSTR+lane]=a5;
  ytq[6*YSTR+lane]=a6;   ytq[7*YSTR+lane]=a7;   ytq[8*YSTR+lane]=a8;
  ytq[9*YSTR+lane]=a9;   ytq[10*YSTR+lane]=a10; ytq[11*YSTR+lane]=a11;
  ytq[12*YSTR+lane]=a12; ytq[13*YSTR+lane]=a13; ytq[14*YSTR+lane]=a14;
  ytq[15*YSTR+lane]=a15;

  const int fl = lane >> 2, c = lane & 3;
  const float* yp = ytq + fl * YSTR + c * 16;
  float4 v0 = *(const float4*)(yp);
  float4 v1 = *(const float4*)(yp + 4);
  float4 v2 = *(const float4*)(yp + 8);
  float4 v3 = *(const float4*)(yp + 12);
  float s1 = ((v0.x+v0.y)+(v0.z+v0.w)) + ((v1.x+v1.y)+(v1.z+v1.w))
           + ((v2.x+v2.y)+(v2.z+v2.w)) + ((v3.x+v3.y)+(v3.z+v3.w));
  float s2 = 0.f;
  s2=fmaf(v0.x,v0.x,s2); s2=fmaf(v0.y,v0.y,s2); s2=fmaf(v0.z,v0.z,s2); s2=fmaf(v0.w,v0.w,s2);
  s2=fmaf(v1.x,v1.x,s2); s2=fmaf(v1.y,v1.y,s2); s2=fmaf(v1.z,v1.z,s2); s2=fmaf(v1.w,v1.w,s2);
  s2=fmaf(v2.x,v2.x,s2); s2=fmaf(v2.y,v2.y,s2); s2=fmaf(v2.z,v2.z,s2); s2=fmaf(v2.w,v2.w,s2);
  s2=fmaf(v3.x,v3.x,s2); s2=fmaf(v3.y,v3.y,s2); s2=fmaf(v3.z,v3.z,s2); s2=fmaf(v3.w,v3.w,s2);

  s1 += __shfl_xor(s1, 1, 64);  s2 += __shfl_xor(s2, 1, 64);
  s1 += __shfl_xor(s1, 2, 64);  s2 += __shfl_xor(s2, 2, 64);

  if (c == 0 && fbase + fl < F) {
    double* slot = acc + ((size_t)(fbase + fl) * NSLC + slice) * 2;
    atomicAdd(slot,     (double)s1);                 // hw f64 atomic
    atomicAdd(slot + 1, (double)s2);
  }
}

// ---------------------------------------------------------------------------
// Final BN: hT -> row-major out. Wave 0 scsh || waves 1-3 stage raw hT.
// ---------------------------------------------------------------------------
__global__ void __launch_bounds__(NTHR, 8)
final_tr_kernel(const float* __restrict__ hT, const double* __restrict__ acc_last,
                const float* __restrict__ g, const float* __restrict__ bt,
                float* __restrict__ out)
{
  __shared__ float2 scsh[64];
  __shared__ float  ybuf[F * 64];
  const int tid  = threadIdx.x;
  const int lane = tid & 63;
  const int qu   = __builtin_amdgcn_readfirstlane(tid >> 6);
  const int rowbase = blockIdx.x * RPB;

  if (qu == 0) {
    scsh_wave0(acc_last, g, bt, scsh, lane);
  } else {
    for (int i = tid - 64; i < F * 16; i += (NTHR - 64)) {
      int j = i >> 4, r4 = i & 15;
      float4 v = *(const float4*)(hT + (size_t)j * B + rowbase + r4 * 4);
      *(float4*)&ybuf[j * 64 + r4 * 4] = v;
    }
  }
  __syncthreads();

  float* oblk = out + (size_t)rowbase * F;
  for (int i = tid; i < RPB * F; i += NTHR) {
    int r = i / F, j = i - r * F;
    float2 s = scsh[j];
    oblk[i] = fmaf(ybuf[j * 64 + r], s.x, s.y);
  }
}

// ---------------------------------------------------------------------------
extern "C" void kernel_launch(void* const* d_in, const int* in_sizes, int n_in,
                              void* d_out, int out_size, void* d_ws, size_t ws_size,
                              hipStream_t stream)
{
  const float* x   = (const float*)d_in[0];
  const float* W0  = (const float*)d_in[1];
  const float* b0  = (const float*)d_in[2];
  const float* g0  = (const float*)d_in[3];
  const float* bt0 = (const float*)d_in[4];
  const float* Ws  = (const float*)d_in[5];
  const float* bs  = (const float*)d_in[6];
  const float* gs  = (const float*)d_in[7];
  const float* bts = (const float*)d_in[8];
  float* out = (float*)d_out;

  double* acc = (double*)d_ws;
  float*  Wt  = (float*)((char*)d_ws + WT_OFF_B);
  float*  bp  = (float*)((char*)d_ws + BP_OFF_B);    // [NB][64]
  float*  hB  = (float*)((char*)d_ws + HB_OFF_B);    // [F][B]
  float*  hA  = out;                                 // [F][B] alias of d_out

  hipMemsetAsync(d_ws, 0, (size_t)ACC_TOTAL * sizeof(double), stream);

  transpose_w<<<NB, NTHR, 0, stream>>>(W0, b0, Ws, Wt, bp);

  // layer 0: x -> hB (raw weights)
  layer_kernel<true><<<NBLK, NTHR, 0, stream>>>(x, Wt, bp, hB, acc);

  // layers 1..14: fuse BN(prev) into weights, then barrier-free layer
  for (int b = 1; b < NB; ++b) {
    const float* gp  = (b == 1) ? g0  : gs  + (size_t)(b - 2) * F;
    const float* btp = (b == 1) ? bt0 : bts + (size_t)(b - 2) * F;
    float* Wpb = Wt + WT0_FLOATS + (size_t)(b - 1) * WTN_FLOATS;
    fuse_w<<<1, NTHR, 0, stream>>>(acc + (size_t)(b - 1) * ACC_PER_LAYER,
                                   gp, btp, bs + (size_t)(b - 1) * F,
                                   Wpb, bp + (size_t)b * 64);
    const float* src = (b & 1) ? hB : hA;
    float*       dst = (b & 1) ? hA : hB;
    layer_kernel<false><<<NBLK, NTHR, 0, stream>>>(
        src, Wpb, bp + (size_t)b * 64, dst, acc + (size_t)b * ACC_PER_LAYER);
  }

  // layer 14 wrote hB -> final BN into row-major d_out
  final_tr_kernel<<<NBLK, NTHR, 0, stream>>>(
      hB, acc + (size_t)(NB - 1) * ACC_PER_LAYER,
      gs + (size_t)(NB - 2) * F, bts + (size_t)(NB - 2) * F, out);
}